// Round 8
// baseline (910.385 us; speedup 1.0000x reference)
//
#include <hip/hip_runtime.h>
#include <hip/hip_cooperative_groups.h>

namespace cg = cooperative_groups;

#define EPS 1e-16f

typedef __attribute__((ext_vector_type(8))) short short8;
typedef __attribute__((ext_vector_type(4))) float f32x4;

// ---------- bf16 <-> fp32 (internal storage only) ----------
__device__ __forceinline__ float b2f(unsigned short u) {
    return __uint_as_float(((unsigned)u) << 16);
}
__device__ __forceinline__ unsigned short f2b(float f) {
    unsigned u = __float_as_uint(f);
    u += 0x7fffu + ((u >> 16) & 1u);  // round-to-nearest-even
    return (unsigned short)(u >> 16);
}

// ---------- async global->LDS (16B per lane; dst = base + lane*16) ----------
typedef __attribute__((address_space(3))) void lds_vp;
typedef __attribute__((address_space(1))) const void glb_vp;
__device__ __forceinline__ void load_lds16(const unsigned short* g,
                                           unsigned short* l) {
    __builtin_amdgcn_global_load_lds((glb_vp*)g, (lds_vp*)l, 16, 0, 0);
}

// ================= merged setup: wprep + pool_init + wa1 =========
// Segmented by blockIdx: [0,WB) wprep, [WB,WB+PB) pool_init, last wa1.
__global__ void setup_kernel(const float* __restrict__ W1,
                             const float* __restrict__ W2,
                             const float* __restrict__ W3,
                             unsigned short* __restrict__ wt2,
                             unsigned short* __restrict__ wt3,
                             unsigned short* __restrict__ w1sk,
                             const float* __restrict__ a1s,
                             const float* __restrict__ a1d,
                             float* __restrict__ w_as,
                             float* __restrict__ w_ad,
                             float* __restrict__ pool, int GC, int WB,
                             int PB) {
    int b = blockIdx.x, t = threadIdx.x;
    if (b < WB) {
        int i = b * 256 + t;
        if (i < 1024 * 512) {
            int k = i / 512, n = i % 512;
            wt2[(size_t)n * 1024 + k] = f2b(W2[i]);
        } else if (i < 1024 * 512 + 512 * 128) {
            int j = i - 1024 * 512;
            int k = j / 128, n = j % 128;
            wt3[(size_t)n * 512 + k] = f2b(W3[j]);
        } else if (i < 1024 * 512 + 512 * 128 + 8 * 128 * 32) {
            int q = i - (1024 * 512 + 512 * 128);
            int h = q >> 12, rem = q & 4095;
            int c = rem >> 5, kk = rem & 31;
            int off = (h == 7) ? 16 : 0;  // 16h - min(16h,96)
            float v = 0.f;
            int k = kk - off;
            if (k >= 0 && k < 11) v = W1[k * 1024 + h * 128 + c];
            w1sk[q] = f2b(v);
        }
    } else if (b < WB + PB) {
        int i = (b - WB) * 256 + t;
        if (i < GC) pool[i] = 0.f;
    } else {
        // wa1: w_as/w_ad = W1^T a1s / a1d, 88 active threads
        if (t < 88) {
            int h = t / 11, k = t % 11;
            float s = 0.f, d = 0.f;
            for (int c = 0; c < 128; c++) {
                float w = W1[k * 1024 + h * 128 + c];
                s += w * a1s[h * 128 + c];
                d += w * a1d[h * 128 + c];
            }
            w_as[h * 16 + k] = s;
            w_ad[h * 16 + k] = d;
        }
    }
}

// ====== cooperative CSR + al1: deg-init, hist||al1, scan, scatter ======
// One launch instead of five; grid.sync() between dependent phases.
// Grid must be co-resident: 977 blocks x 256 thr, ~1.3 KB LDS, low VGPR.
__global__ void csr_coop(const int* __restrict__ ei, int E, int N,
                         int* __restrict__ deg, int* __restrict__ rowst,
                         int* __restrict__ bsum, int* __restrict__ boff,
                         int* __restrict__ srcs, int* __restrict__ cursor,
                         const float* __restrict__ x,
                         const float* __restrict__ w_as,
                         const float* __restrict__ w_ad,
                         float* __restrict__ als, float* __restrict__ ald,
                         int NB) {
    cg::grid_group grid = cg::this_grid();
    int nbk = gridDim.x;
    int t = threadIdx.x;
    int gtid = blockIdx.x * 256 + t;
    int gstride = nbk * 256;
    __shared__ int s[256];
    __shared__ int psum[65];

    // phase 0: deg init (self-loop)
    for (int i = gtid; i < N; i += gstride) deg[i] = 1;
    grid.sync();

    // phase 1: hist atomics || al1 logits (independent)
    for (int e = gtid; e < E; e += gstride) {
        int d = ei[E + e];
        if ((unsigned)d < (unsigned)N) atomicAdd(&deg[d], 1);
    }
    for (int i = gtid; i < N * 8; i += gstride) {
        int n = i >> 3, h = i & 7;
        float sa = 0.f, da = 0.f;
#pragma unroll
        for (int k = 0; k < 11; k++) {
            float xv = x[n * 11 + k];
            sa += xv * w_as[h * 16 + k];
            da += xv * w_ad[h * 16 + k];
        }
        als[i] = sa;
        ald[i] = da;
    }
    grid.sync();

    // phase 2a: block-level inclusive scan of deg -> rowst[i+1], bsum
    for (int b = blockIdx.x; b < NB; b += nbk) {
        int i = b * 256 + t;
        s[t] = (i < N) ? deg[i] : 0;
        __syncthreads();
        for (int o = 1; o < 256; o <<= 1) {
            int a = (t >= o) ? s[t - o] : 0;
            __syncthreads();
            s[t] += a;
            __syncthreads();
        }
        if (i < N) rowst[i + 1] = s[t];
        if (t == 255) bsum[b] = s[255];
        __syncthreads();
    }
    grid.sync();

    // phase 2b: top-level scan of bsum -> boff (block 0 only, all 256 thr
    // hit the barriers uniformly; only t<64 do work)
    if (blockIdx.x == 0) {
        int chunk = (NB + 63) / 64;
        int lo = 0, hi = 0, acc = 0;
        if (t < 64) {
            lo = t * chunk;
            hi = lo + chunk;
            if (lo > NB) lo = NB;
            if (hi > NB) hi = NB;
            for (int i = lo; i < hi; i++) acc += bsum[i];
            psum[t + 1] = acc;
        }
        __syncthreads();
        if (t == 0) {
            psum[0] = 0;
            for (int i = 1; i <= 64; i++) psum[i] += psum[i - 1];
        }
        __syncthreads();
        if (t < 64) {
            int run = psum[t];
            for (int i = lo; i < hi; i++) {
                boff[i] = run;  // exclusive
                run += bsum[i];
            }
        }
    }
    grid.sync();

    // phase 2c: finish scan + place self-loop + init cursor
    for (int b = blockIdx.x; b < NB; b += nbk) {
        int i = b * 256 + t;
        if (i == 0) rowst[0] = 0;
        if (i < N) {
            int incl = rowst[i + 1] + boff[b];
            rowst[i + 1] = incl;
            int st = incl - deg[i];
            srcs[st] = i;  // self-loop at row head
            cursor[i] = st + 1;
        }
    }
    grid.sync();

    // phase 3: scatter edges (resolve src at build time)
    for (int e = gtid; e < E; e += gstride) {
        int d = ei[E + e];
        if ((unsigned)d < (unsigned)N) {
            int p = atomicAdd(&cursor[d], 1);
            int sv = ei[e];
            if ((unsigned)sv >= (unsigned)N) sv = d;
            srcs[p] = sv;
        }
    }
}

// ------ fused layer-1 softmax + x-aggregation ------
__global__ void agg1_fused(const float* __restrict__ x,
                           const float* __restrict__ als,
                           const float* __restrict__ ald,
                           const int* __restrict__ rowst,
                           const int* __restrict__ srcs,
                           unsigned short* __restrict__ A2, int N) {
    constexpr int MAXE = 64;
    __shared__ float sv[MAXE * 8];
    __shared__ float sx[MAXE * 12];  // 11 cols, pad to 12
    int n = blockIdx.x;
    int t = threadIdx.x;  // 128
    int h = t >> 4, k = t & 15;
    int start = rowst[n], end = rowst[n + 1];
    int deg = end - start;
    float acc = 0.f;

    if (deg <= MAXE) {
        // phase A: each (edge,head) logit exactly once + x-row stage
        for (int p = t; p < deg * 8; p += 128) {
            int e = p >> 3, hh = p & 7;
            int s = srcs[start + e];
            float v = als[s * 8 + hh] + ald[n * 8 + hh];
            sv[e * 8 + hh] = v > 0.f ? v : 0.2f * v;
        }
        for (int p = t; p < deg * 16; p += 128) {
            int e = p >> 4, kx = p & 15;
            if (kx < 11)
                sx[e * 12 + kx] = x[(size_t)srcs[start + e] * 11 + kx];
        }
        __syncthreads();
        // phase B: per-head softmax (16-lane reduce)
        float m = -1e30f;
        for (int e = k; e < deg; e += 16) m = fmaxf(m, sv[e * 8 + h]);
#pragma unroll
        for (int o = 1; o < 16; o <<= 1) m = fmaxf(m, __shfl_xor(m, o));
        float ee[(MAXE + 15) / 16];
        float den = 0.f;
        {
            int kk = 0;
            for (int e = k; e < deg; e += 16, kk++) {
                float xv = expf(sv[e * 8 + h] - m);
                ee[kk] = xv;
                den += xv;
            }
        }
#pragma unroll
        for (int o = 1; o < 16; o <<= 1) den += __shfl_xor(den, o);
        float dinv = 1.0f / (den + EPS);
        {
            int kk = 0;
            for (int e = k; e < deg; e += 16, kk++)
                sv[e * 8 + h] = ee[kk] * dinv;
        }
        __syncthreads();
        // phase C: pure LDS FMA
        const int CH = 4;
        for (int e = 0; e < deg; e += CH) {
            int mc = deg - e;
            if (mc > CH) mc = CH;
            float al[CH], xv[CH];
#pragma unroll
            for (int j = 0; j < CH; j++)
                if (j < mc) {
                    al[j] = sv[(e + j) * 8 + h];
                    xv[j] = (k < 11) ? sx[(e + j) * 12 + k] : 0.f;
                }
#pragma unroll
            for (int j = 0; j < CH; j++)
                if (j < mc) acc += al[j] * xv[j];
        }
    } else {
        // slow path (deg > 64, rare): recompute alpha on the fly
        float aldn = ald[n * 8 + h];
        float m = -1e30f;
        for (int idx = start + k; idx < end; idx += 16) {
            float v = als[srcs[idx] * 8 + h] + aldn;
            v = v > 0.f ? v : 0.2f * v;
            m = fmaxf(m, v);
        }
#pragma unroll
        for (int o = 1; o < 16; o <<= 1) m = fmaxf(m, __shfl_xor(m, o));
        float den = 0.f;
        for (int idx = start + k; idx < end; idx += 16) {
            float v = als[srcs[idx] * 8 + h] + aldn;
            v = v > 0.f ? v : 0.2f * v;
            den += expf(v - m);
        }
#pragma unroll
        for (int o = 1; o < 16; o <<= 1) den += __shfl_xor(den, o);
        float dinv = 1.0f / (den + EPS);
        for (int idx = start; idx < end; idx++) {
            int s = srcs[idx];
            float v = als[s * 8 + h] + aldn;
            v = v > 0.f ? v : 0.2f * v;
            float a = expf(v - m) * dinv;
            float xv = (k < 11) ? x[s * 11 + k] : 0.f;
            acc += a * xv;
        }
    }
    A2[(size_t)n * 128 + t] = f2b(acc);
}

// MFMA GEMM (legacy 2-phase, BK=32): used only for layer-1 small-K path.
template <bool EPI, int HB, int CC, bool SK>
__global__ __launch_bounds__(256) void gemm_mfma(
    const unsigned short* __restrict__ A, const unsigned short* __restrict__ Bt,
    unsigned short* __restrict__ C, const float* __restrict__ bias,
    const float* __restrict__ a_s, const float* __restrict__ a_d,
    float* __restrict__ als, float* __restrict__ ald, int H, int M, int N,
    int K, int lda) {
    int NX = gridDim.x;
    int bid = blockIdx.y * NX + blockIdx.x;
    int win = bid & (8 * NX - 1);
    int mg = bid / (8 * NX);
    int m_t = mg * 8 + (win & 7);
    int n_t = win >> 3;
    int bm = m_t * 128, bn = n_t * 128;
    if (bm >= M) return;

    union SMem {
        struct {
            unsigned short As[2][128 * 32];
            unsigned short Bs[2][128 * 32];
        } k;                            // 32 KB, live during K-loop
        unsigned short Ct[128 * 132];   // 33.8 KB, live during epilogue
    };
    __shared__ __align__(16) SMem sm;
    auto& As = sm.k.As;
    auto& Bs = sm.k.Bs;
    auto& Ct = sm.Ct;

    int t = threadIdx.x;
    int w = t >> 6, lane = t & 63;
    int quad = lane >> 4, l16 = lane & 15;
    int wr = (w >> 1) * 64, wc = (w & 1) * 64;

    int kofs = 0;
    const unsigned short* Bb = Bt;
    if (SK) {
        kofs = n_t * 16;
        if (kofs > lda - 32) kofs = lda - 32;
        Bb = Bt + (size_t)n_t * 128 * 32;
    }

    int c0 = w * 128 + lane;
    int c1 = c0 + 64;
    int r0 = c0 >> 2, p0 = c0 & 3;
    int r1 = c1 >> 2, p1 = c1 & 3;
    int j0 = (p0 - (r0 >> 1)) & 3;
    int j1 = (p1 - (r1 >> 1)) & 3;
    int ga0 = bm + r0;
    if (ga0 >= M) ga0 = M - 1;
    int ga1 = bm + r1;
    if (ga1 >= M) ga1 = M - 1;
    const unsigned short* Ag0 = A + (size_t)ga0 * lda + kofs + j0 * 8;
    const unsigned short* Ag1 = A + (size_t)ga1 * lda + kofs + j1 * 8;
    size_t br0 = SK ? (size_t)r0 : (size_t)(bn + r0);
    size_t br1 = SK ? (size_t)r1 : (size_t)(bn + r1);
    const unsigned short* Bg0 = Bb + br0 * K + j0 * 8;
    const unsigned short* Bg1 = Bb + br1 * K + j1 * 8;

    auto stage = [&](int st, int k0) {
        load_lds16(Ag0 + k0, &As[st][(w * 128) * 8]);
        load_lds16(Ag1 + k0, &As[st][(w * 128 + 64) * 8]);
        load_lds16(Bg0 + k0, &Bs[st][(w * 128) * 8]);
        load_lds16(Bg1 + k0, &Bs[st][(w * 128 + 64) * 8]);
    };

    int aoff[4], boff4[4];
#pragma unroll
    for (int i = 0; i < 4; i++) {
        int ra = wr + i * 16 + l16;
        aoff[i] = ra * 32 + (((quad + (ra >> 1)) & 3) * 8);
        int rb = wc + i * 16 + l16;
        boff4[i] = rb * 32 + (((quad + (rb >> 1)) & 3) * 8);
    }

    f32x4 acc[4][4] = {};
    stage(0, 0);
    int st = 0;
    for (int k0 = 0; k0 < K; k0 += 32, st ^= 1) {
        __syncthreads();
        if (k0 + 32 < K) stage(st ^ 1, k0 + 32);
        short8 a[4], b[4];
#pragma unroll
        for (int mi = 0; mi < 4; mi++) a[mi] = *(const short8*)&As[st][aoff[mi]];
#pragma unroll
        for (int ni = 0; ni < 4; ni++) b[ni] = *(const short8*)&Bs[st][boff4[ni]];
#pragma unroll
        for (int mi = 0; mi < 4; mi++)
#pragma unroll
            for (int ni = 0; ni < 4; ni++)
                acc[mi][ni] = __builtin_amdgcn_mfma_f32_16x16x32_bf16(
                    a[mi], b[ni], acc[mi][ni], 0, 0, 0);
    }
    __syncthreads();  // all waves done with As/Bs before Ct overlays them

#pragma unroll
    for (int mi = 0; mi < 4; mi++) {
#pragma unroll
        for (int r = 0; r < 4; r++) {
            int rl = wr + mi * 16 + quad * 4 + r;
#pragma unroll
            for (int ni = 0; ni < 4; ni++) {
                int cl = wc + ni * 16 + l16;
                float v = acc[mi][ni][r];
                if (EPI) {
                    v += bias[bn + cl];
                    v = v > 0.f ? v : 0.01f * v;
                }
                Ct[rl * 132 + cl] = f2b(v);
            }
        }
    }
    __syncthreads();
#pragma unroll
    for (int p = 0; p < 16; p++) {
        int q = p * 256 + t;
        int row = q >> 5, c8 = q & 31;
        if (bm + row < M) {
            uint2 v = *(const uint2*)&Ct[row * 132 + c8 * 4];
            *(uint2*)&C[(size_t)(bm + row) * N + bn + c8 * 4] = v;
        }
    }
    if (HB > 0) {
        for (int pi = t; pi < 128 * HB; pi += 256) {
            int row = pi / HB, hl = pi % HB;
            if (bm + row >= M) continue;
            int hg = bn / CC + hl;
            const unsigned short* rp = &Ct[row * 132 + hl * CC];
            const float* asp = a_s + hg * CC;
            const float* adp = a_d + hg * CC;
            float s = 0.f, d = 0.f;
#pragma unroll
            for (int c = 0; c < CC; c++) {
                float v = b2f(rp[c]);
                s += v * asp[c];
                d += v * adp[c];
            }
            als[(size_t)(bm + row) * H + hg] = s;
            ald[(size_t)(bm + row) * H + hg] = d;
        }
    }
}

// ================== pipelined MFMA GEMM (layers 2 & 3) ==================
// BM=BN=128, BK=64, 4 waves (64x64 each), double-buffered 64 KB LDS.
// Counted-vmcnt schedule; raw s_barrier; XOR slot swizzle with
// inverse-swizzled global source. K % 64 == 0, lda == K, N % 128 == 0.
// At 2 blocks/CU this runs at the per-CU LDS-BW roofline (~124 B/cyc).
template <int HB, int CC>
__global__ __launch_bounds__(256, 2) void gemm_pipe(
    const unsigned short* __restrict__ A, const unsigned short* __restrict__ Bt,
    unsigned short* __restrict__ C, const float* __restrict__ a_s,
    const float* __restrict__ a_d, float* __restrict__ als,
    float* __restrict__ ald, int H, int M, int N, int K) {
    int NX = gridDim.x;
    int bid = blockIdx.y * NX + blockIdx.x;
    int win = bid & (8 * NX - 1);
    int mg = bid / (8 * NX);
    int m_t = mg * 8 + (win & 7);
    int n_t = win >> 3;
    int bm = m_t * 128, bn = n_t * 128;
    if (bm >= M) return;

    union SMem {
        struct {
            unsigned short As[2][128 * 64];
            unsigned short Bs[2][128 * 64];
        } k;                            // 64 KB, live during K-loop
        unsigned short Ct[128 * 132];   // 33.8 KB, live during epilogue
    };
    __shared__ __align__(16) SMem sm;

    int t = threadIdx.x;
    int w = t >> 6, lane = t & 63;
    int quad = lane >> 4, l16 = lane & 15;
    int wr = (w >> 1) * 64, wc = (w & 1) * 64;

    int srow = lane >> 3;            // row&7 for this lane's chunks
    int gsl = (lane & 7) ^ srow;     // inverse-swizzled global slot
    const unsigned short* Ag[4];
    const unsigned short* Bg[4];
#pragma unroll
    for (int j = 0; j < 4; j++) {
        int row = (j * 4 + w) * 8 + srow;  // 0..127
        int ga = bm + row;
        if (ga > M - 1) ga = M - 1;
        Ag[j] = A + (size_t)ga * K + gsl * 8;
        Bg[j] = Bt + (size_t)(bn + row) * K + gsl * 8;
    }
    auto stage = [&](int st, int kt) {
        int ko = kt * 64;
#pragma unroll
        for (int j = 0; j < 4; j++) {
            load_lds16(Ag[j] + ko, &sm.k.As[st][(j * 4 + w) * 512]);
            load_lds16(Bg[j] + ko, &sm.k.Bs[st][(j * 4 + w) * 512]);
        }
    };

    int arow[4], brow[4];
#pragma unroll
    for (int i = 0; i < 4; i++) {
        arow[i] = (wr + i * 16 + l16) * 64;
        brow[i] = (wc + i * 16 + l16) * 64;
    }
    int sw = l16 & 7;

    f32x4 acc[4][4] = {};
    int NT = K >> 6;
    stage(0, 0);
    if (NT > 1) stage(1, 1);
    for (int tt = 0; tt < NT; tt++) {
        int bb = tt & 1;
        if (tt + 1 < NT)
            asm volatile("s_waitcnt vmcnt(8)" ::: "memory");
        else
            asm volatile("s_waitcnt vmcnt(0)" ::: "memory");
        __builtin_amdgcn_s_barrier();
        __builtin_amdgcn_sched_barrier(0);  // no frag read above the barrier
#pragma unroll
        for (int ks = 0; ks < 2; ks++) {
            short8 a[4], b[4];
            int so = ((ks * 4 + quad) ^ sw) * 8;
#pragma unroll
            for (int mi = 0; mi < 4; mi++)
                a[mi] = *(const short8*)&sm.k.As[bb][arow[mi] + so];
#pragma unroll
            for (int ni = 0; ni < 4; ni++)
                b[ni] = *(const short8*)&sm.k.Bs[bb][brow[ni] + so];
            __builtin_amdgcn_s_setprio(1);
#pragma unroll
            for (int mi = 0; mi < 4; mi++)
#pragma unroll
                for (int ni = 0; ni < 4; ni++)
                    acc[mi][ni] = __builtin_amdgcn_mfma_f32_16x16x32_bf16(
                        a[mi], b[ni], acc[mi][ni], 0, 0, 0);
            __builtin_amdgcn_s_setprio(0);
        }
        asm volatile("s_waitcnt lgkmcnt(0)" ::: "memory");
        __builtin_amdgcn_s_barrier();  // all waves done reading buf bb
        if (tt + 2 < NT) stage(bb, tt + 2);
    }
    __syncthreads();  // K-loop fully drained before Ct overlays As/Bs

#pragma unroll
    for (int mi = 0; mi < 4; mi++) {
#pragma unroll
        for (int r = 0; r < 4; r++) {
            int rl = wr + mi * 16 + quad * 4 + r;
#pragma unroll
            for (int ni = 0; ni < 4; ni++) {
                int cl = wc + ni * 16 + l16;
                sm.Ct[rl * 132 + cl] = f2b(acc[mi][ni][r]);
            }
        }
    }
    __syncthreads();
#pragma unroll
    for (int p = 0; p < 16; p++) {
        int q = p * 256 + t;
        int row = q >> 5, c8 = q & 31;
        if (bm + row < M) {
            uint2 v = *(const uint2*)&sm.Ct[row * 132 + c8 * 4];
            *(uint2*)&C[(size_t)(bm + row) * N + bn + c8 * 4] = v;
        }
    }
    if (HB > 0) {
        for (int pi = t; pi < 128 * HB; pi += 256) {
            int row = pi / HB, hl = pi % HB;
            if (bm + row >= M) continue;
            int hg = bn / CC + hl;
            const unsigned short* rp = &sm.Ct[row * 132 + hl * CC];
            const float* asp = a_s + hg * CC;
            const float* adp = a_d + hg * CC;
            float s = 0.f, d = 0.f;
#pragma unroll
            for (int c = 0; c < CC; c++) {
                float v = b2f(rp[c]);
                s += v * asp[c];
                d += v * adp[c];
            }
            als[(size_t)(bm + row) * H + hg] = s;
            ald[(size_t)(bm + row) * H + hg] = d;
        }
    }
}

// ------ fused softmax + aggregation, 1 wave, 8 cols/thread (layer 2) ------
// 64 threads; thread t owns cols c=t*8..t*8+7 of head hh=t>>3; TPH=8.
// ushort8 gathers: 16 B/lane -> one full 1 KB row per wave instruction.
// Per-column accumulation order identical to previous version.
template <int H, int C>
__global__ void agg_fused4(const unsigned short* __restrict__ hin,
                           const float* __restrict__ als,
                           const float* __restrict__ ald,
                           const int* __restrict__ rowst,
                           const int* __restrict__ srcs,
                           const float* __restrict__ bias,
                           unsigned short* __restrict__ out, int N) {
    constexpr int HC = H * C;        // 512
    constexpr int NT = HC / 8;       // 64 threads
    constexpr int TPH = C / 8;       // 8 lanes per head
    constexpr int MAXE = 64;
    __shared__ float sv[MAXE * H];   // logits -> alphas
    __shared__ int ssrc[MAXE];
    int n = blockIdx.x;
    int t = threadIdx.x;
    int c = t * 8;
    int hh = c / C;
    int li = (c % C) / 8;
    int start = rowst[n], end = rowst[n + 1];
    int deg = end - start;
    float acc[8] = {};

    if (deg <= MAXE) {
        // phase A: each (edge,head) logit exactly once
        for (int p = t; p < deg * H; p += NT) {
            int e = p / H, h = p % H;
            int s = srcs[start + e];
            if (h == 0) ssrc[e] = s;
            float v = als[s * H + h] + ald[n * H + h];
            sv[e * H + h] = v > 0.f ? v : 0.2f * v;
        }
        __syncthreads();
        // phase B: per-head softmax (8-lane reduce)
        float m = -1e30f;
        for (int e = li; e < deg; e += TPH) m = fmaxf(m, sv[e * H + hh]);
#pragma unroll
        for (int o = 1; o < TPH; o <<= 1) m = fmaxf(m, __shfl_xor(m, o));
        float ee[(MAXE + TPH - 1) / TPH];
        float den = 0.f;
        {
            int k = 0;
            for (int e = li; e < deg; e += TPH, k++) {
                float x = expf(sv[e * H + hh] - m);
                ee[k] = x;
                den += x;
            }
        }
#pragma unroll
        for (int o = 1; o < TPH; o <<= 1) den += __shfl_xor(den, o);
        float dinv = 1.0f / (den + EPS);
        {
            int k = 0;
            for (int e = li; e < deg; e += TPH, k++)
                sv[e * H + hh] = ee[k] * dinv;
        }
        __syncthreads();
        // phase C: pure gather + FMA (16 B loads)
        const int CH = 4;
        for (int e = 0; e < deg; e += CH) {
            int mc = deg - e;
            if (mc > CH) mc = CH;
            int ss[CH];
            float al[CH];
            short8 uv[CH];
#pragma unroll
            for (int j = 0; j < CH; j++)
                if (j < mc) {
                    ss[j] = ssrc[e + j];
                    al[j] = sv[(e + j) * H + hh];
                }
#pragma unroll
            for (int j = 0; j < CH; j++)
                if (j < mc)
                    uv[j] = *(const short8*)(hin + (size_t)ss[j] * HC + c);
#pragma unroll
            for (int j = 0; j < CH; j++)
                if (j < mc) {
                    float a = al[j];
#pragma unroll
                    for (int q = 0; q < 8; q++)
                        acc[q] += a * b2f((unsigned short)uv[j][q]);
                }
        }
    } else {
        // slow path (deg > MAXE, rare): per-thread recompute
        float aldn = ald[n * H + hh];
        float m = -1e30f;
        for (int idx = start + li; idx < end; idx += TPH) {
            float v = als[srcs[idx] * H + hh] + aldn;
            v = v > 0.f ? v : 0.2f * v;
            m = fmaxf(m, v);
        }
#pragma unroll
        for (int o = 1; o < TPH; o <<= 1) m = fmaxf(m, __shfl_xor(m, o));
        float den = 0.f;
        for (int idx = start + li; idx < end; idx += TPH) {
            float v = als[srcs[idx] * H + hh] + aldn;
            v = v > 0.f ? v : 0.2f * v;
            den += expf(v - m);
        }
#pragma unroll
        for (int o = 1; o < TPH; o <<= 1) den += __shfl_xor(den, o);
        float dinv = 1.0f / (den + EPS);
        for (int idx = start; idx < end; idx++) {
            int s = srcs[idx];
            float v = als[s * H + hh] + aldn;
            v = v > 0.f ? v : 0.2f * v;
            float a = expf(v - m) * dinv;
            short8 uv = *(const short8*)(hin + (size_t)s * HC + c);
#pragma unroll
            for (int q = 0; q < 8; q++)
                acc[q] += a * b2f((unsigned short)uv[q]);
        }
    }
    short8 o8;
#pragma unroll
    for (int q = 0; q < 8; q++) {
        float v = acc[q] + bias[c + q];
        v = v > 0.f ? v : 0.01f * v;
        o8[q] = (short)f2b(v);
    }
    *(short8*)&out[(size_t)n * HC + c] = o8;
}

// ------ fused softmax + aggregation, ushort2 (layer 3) ------
template <int H, int C>
__global__ void agg_fused2(const unsigned short* __restrict__ hin,
                           const float* __restrict__ als,
                           const float* __restrict__ ald,
                           const int* __restrict__ rowst,
                           const int* __restrict__ srcs,
                           const float* __restrict__ bias,
                           unsigned short* __restrict__ out, int N) {
    constexpr int HC = H * C;        // 128
    constexpr int NT = HC / 2;       // 64 threads
    constexpr int TPH = C / 2;       // 16 lanes per head
    constexpr int MAXE = 64;
    __shared__ float sv[MAXE * H];
    __shared__ int ssrc[MAXE];
    int n = blockIdx.x;
    int t = threadIdx.x;
    int c = t * 2;
    int hh = c / C;
    int li = (c % C) / 2;
    int start = rowst[n], end = rowst[n + 1];
    int deg = end - start;
    float a0 = 0.f, a1 = 0.f;

    if (deg <= MAXE) {
        for (int p = t; p < deg * H; p += NT) {
            int e = p / H, h = p % H;
            int s = srcs[start + e];
            if (h == 0) ssrc[e] = s;
            float v = als[s * H + h] + ald[n * H + h];
            sv[e * H + h] = v > 0.f ? v : 0.2f * v;
        }
        __syncthreads();
        float m = -1e30f;
        for (int e = li; e < deg; e += TPH) m = fmaxf(m, sv[e * H + hh]);
#pragma unroll
        for (int o = 1; o < TPH; o <<= 1) m = fmaxf(m, __shfl_xor(m, o));
        float ee[(MAXE + TPH - 1) / TPH];
        float den = 0.f;
        {
            int k = 0;
            for (int e = li; e < deg; e += TPH, k++) {
                float x = expf(sv[e * H + hh] - m);
                ee[k] = x;
                den += x;
            }
        }
#pragma unroll
        for (int o = 1; o < TPH; o <<= 1) den += __shfl_xor(den, o);
        float dinv = 1.0f / (den + EPS);
        {
            int k = 0;
            for (int e = li; e < deg; e += TPH, k++)
                sv[e * H + hh] = ee[k] * dinv;
        }
        __syncthreads();
        const int CH = 4;
        for (int e = 0; e < deg; e += CH) {
            int mc = deg - e;
            if (mc > CH) mc = CH;
            int ss[CH];
            float al[CH];
            ushort2 uv[CH];
#pragma unroll
            for (int j = 0; j < CH; j++)
                if (j < mc) {
                    ss[j] = ssrc[e + j];
                    al[j] = sv[(e + j) * H + hh];
                }
#pragma unroll
            for (int j = 0; j < CH; j++)
                if (j < mc)
                    uv[j] = *(const ushort2*)(hin + (size_t)ss[j] * HC + c);
#pragma unroll
            for (int j = 0; j < CH; j++)
                if (j < mc) {
                    a0 += al[j] * b2f(uv[j].x);
                    a1 += al[j] * b2f(uv[j].y);
                }
        }
    } else {
        float aldn = ald[n * H + hh];
        float m = -1e30f;
        for (int idx = start + li; idx < end; idx += TPH) {
            float v = als[srcs[idx] * H + hh] + aldn;
            v = v > 0.f ? v : 0.2f * v;
            m = fmaxf(m, v);
        }
#pragma unroll
        for (int o = 1; o < TPH; o <<= 1) m = fmaxf(m, __shfl_xor(m, o));
        float den = 0.f;
        for (int idx = start + li; idx < end; idx += TPH) {
            float v = als[srcs[idx] * H + hh] + aldn;
            v = v > 0.f ? v : 0.2f * v;
            den += expf(v - m);
        }
#pragma unroll
        for (int o = 1; o < TPH; o <<= 1) den += __shfl_xor(den, o);
        float dinv = 1.0f / (den + EPS);
        const int CH = 4;
        for (int idx = start; idx < end; idx += CH) {
            int mc = end - idx;
            if (mc > CH) mc = CH;
            int ss[CH];
            float lv[CH];
            ushort2 uv[CH];
#pragma unroll
            for (int j = 0; j < CH; j++)
                if (j < mc) ss[j] = srcs[idx + j];
#pragma unroll
            for (int j = 0; j < CH; j++)
                if (j < mc) lv[j] = als[ss[j] * H + hh];
#pragma unroll
            for (int j = 0; j < CH; j++)
                if (j < mc)
                    uv[j] = *(const ushort2*)(hin + (size_t)ss[j] * HC + c);
#pragma unroll
            for (int j = 0; j < CH; j++)
                if (j < mc) {
                    float v = lv[j] + aldn;
                    v = v > 0.f ? v : 0.2f * v;
                    float a = expf(v - m) * dinv;
                    a0 += a * b2f(uv[j].x);
                    a1 += a * b2f(uv[j].y);
                }
        }
    }
    float v0 = a0 + bias[c], v1 = a1 + bias[c + 1];
    ushort2 o;
    o.x = f2b(v0 > 0.f ? v0 : 0.01f * v0);
    o.y = f2b(v1 > 0.f ? v1 : 0.01f * v1);
    *(ushort2*)&out[(size_t)n * HC + c] = o;
}

// ---------------------- parallel mean-pool + head ----------------------
__global__ void pool_partial_kernel(const unsigned short* __restrict__ h3,
                                    const int* __restrict__ batch,
                                    float* __restrict__ pool, int N, int G) {
    int lo = blockIdx.x * 128;
    int hi = lo + 128;
    if (hi > N) hi = N;
    if (lo >= N) return;
    int t = threadIdx.x;  // 128
    int cur = batch[lo];
    float acc = 0.f;
    for (int n = lo; n < hi; n++) {
        int g = batch[n];
        if (g != cur) {
            if ((unsigned)cur < (unsigned)G) atomicAdd(&pool[cur * 128 + t], acc);
            acc = 0.f;
            cur = g;
        }
        acc += b2f(h3[(size_t)n * 128 + t]);
    }
    if ((unsigned)cur < (unsigned)G) atomicAdd(&pool[cur * 128 + t], acc);
}

__global__ void head_kernel(const float* __restrict__ pool,
                            const int* __restrict__ batch,
                            const float* __restrict__ Wout,
                            const float* __restrict__ bout,
                            float* __restrict__ out, int N) {
    int g = blockIdx.x;
    int t = threadIdx.x;  // 128
    int lo, hi;
    {
        int a = 0, b = N;
        while (a < b) { int mid = (a + b) >> 1; if (batch[mid] < g) a = mid + 1; else b = mid; }
        lo = a;
        a = lo; b = N;
        while (a < b) { int mid = (a + b) >> 1; if (batch[mid] < g + 1) a = mid + 1; else b = mid; }
        hi = a;
    }
    float c = (float)(hi - lo);
    c = c > 1.f ? c : 1.f;
    float v = (pool[g * 128 + t] / c) * Wout[t];
    for (int o = 32; o; o >>= 1) v += __shfl_xor(v, o);
    __shared__ float partial[2];
    if ((t & 63) == 0) partial[t >> 6] = v;
    __syncthreads();
    if (t == 0) out[g] = partial[0] + partial[1] + bout[0];
}

// ---------------------------- host orchestration ----------------------------
extern "C" void kernel_launch(void* const* d_in, const int* in_sizes, int n_in,
                              void* d_out, int out_size, void* d_ws,
                              size_t ws_size, hipStream_t stream) {
    const float* x = (const float*)d_in[0];
    const int* ei = (const int*)d_in[1];
    const int* batch = (const int*)d_in[2];
    const float* W1 = (const float*)d_in[3];
    const float* a1s = (const float*)d_in[4];
    const float* a1d = (const float*)d_in[5];
    const float* b1 = (const float*)d_in[6];
    const float* W2 = (const float*)d_in[7];
    const float* a2s = (const float*)d_in[8];
    const float* a2d = (const float*)d_in[9];
    const float* b2 = (const float*)d_in[10];
    const float* W3 = (const float*)d_in[11];
    const float* a3s = (const float*)d_in[12];
    const float* a3d = (const float*)d_in[13];
    const float* b3 = (const float*)d_in[14];
    const float* Wout = (const float*)d_in[15];
    const float* bout = (const float*)d_in[16];
    float* out = (float*)d_out;

    const int N = in_sizes[0] / 11;
    const int E = in_sizes[1] / 2;
    const int Etot = E + N;
    const int G = out_size;
    const int NB = (N + 255) / 256;
    const int MT = ((N + 127) / 128 + 7) / 8 * 8;  // M-tiles padded to x8

    char* ws = (char*)d_ws;
    size_t off = 0;
    auto alloc = [&](size_t bytes) -> void* {
        void* p = ws + off;
        off += (bytes + 255) & ~(size_t)255;
        return p;
    };
    unsigned short* buf1 = (unsigned short*)alloc((size_t)N * 1024 * 2);  // h
    unsigned short* buf2 = (unsigned short*)alloc((size_t)N * 1024 * 2);  // out
    float* als = (float*)alloc((size_t)N * 8 * 4);
    float* ald = (float*)alloc((size_t)N * 8 * 4);
    int* rowst = (int*)alloc((size_t)(N + 1) * 4);
    int* cursor = (int*)alloc((size_t)N * 4);
    int* srcs = (int*)alloc((size_t)Etot * 4);
    int* deg = (int*)alloc((size_t)N * 4);
    int* bsum = (int*)alloc((size_t)NB * 4);
    int* boff = (int*)alloc((size_t)NB * 4);
    float* pool = (float*)alloc((size_t)G * 128 * 4);
    unsigned short* aggx = (unsigned short*)alloc((size_t)N * 128 * 2);
    unsigned short* w1sk = (unsigned short*)alloc((size_t)8 * 128 * 32 * 2);
    unsigned short* wt2 = (unsigned short*)alloc((size_t)1024 * 512 * 2);
    unsigned short* wt3 = (unsigned short*)alloc((size_t)512 * 128 * 2);
    float* w_as = (float*)alloc(8 * 16 * 4);
    float* w_ad = (float*)alloc(8 * 16 * 4);

    int eb = (E + 255) / 256;

    // ---- merged setup: wprep + pool_init + wa1 (1 launch) ----
    const int WTOT = 1024 * 512 + 512 * 128 + 8 * 128 * 32;
    const int WB = (WTOT + 255) / 256;
    const int PB = (G * 128 + 255) / 256;
    setup_kernel<<<WB + PB + 1, 256, 0, stream>>>(W1, W2, W3, wt2, wt3, w1sk,
                                                  a1s, a1d, w_as, w_ad, pool,
                                                  G * 128, WB, PB);

    // ---- cooperative CSR + al1 (replaces 5 launches) ----
    {
        int GB = eb;  // 977 blocks x 256 thr: co-resident (~4 blocks/CU)
        int Ev = E, Nv = N, NBv = NB;
        void* args[] = {(void*)&ei,   (void*)&Ev,     (void*)&Nv,
                        (void*)&deg,  (void*)&rowst,  (void*)&bsum,
                        (void*)&boff, (void*)&srcs,   (void*)&cursor,
                        (void*)&x,    (void*)&w_as,   (void*)&w_ad,
                        (void*)&als,  (void*)&ald,    (void*)&NBv};
        hipLaunchCooperativeKernel((void*)csr_coop, dim3(GB), dim3(256), args,
                                   0, stream);
    }

    // ---- Layer 1 (linearity trick) ----
    agg1_fused<<<N, 128, 0, stream>>>(x, als, ald, rowst, srcs, aggx, N);
    gemm_mfma<true, 0, 1, true><<<dim3(8, MT), 256, 0, stream>>>(
        aggx, w1sk, buf2, b1, nullptr, nullptr, nullptr, nullptr, 0, N, 1024,
        32, 128);

    // ---- Layer 2: pipelined gemm (h2 + fused al) -> fused softmax+agg ----
    gemm_pipe<2, 64><<<dim3(4, MT), 256, 0, stream>>>(
        buf2, wt2, buf1, a2s, a2d, als, ald, 8, N, 512, 1024);
    agg_fused4<8, 64><<<N, 64, 0, stream>>>(buf1, als, ald, rowst, srcs, b2,
                                            buf2, N);

    // ---- Layer 3: pipelined gemm (h3 + fused al) -> fused softmax+agg ----
    gemm_pipe<4, 32><<<dim3(1, MT), 256, 0, stream>>>(
        buf2, wt3, buf1, a3s, a3d, als, ald, 4, N, 128, 512);
    agg_fused2<4, 32><<<N, 64, 0, stream>>>(buf1, als, ald, rowst, srcs, b3,
                                            buf2, N);

    // ---- parallel mean-pool + head ----
    pool_partial_kernel<<<(N + 127) / 128, 128, 0, stream>>>(buf2, batch, pool,
                                                             N, G);
    head_kernel<<<G, 128, 0, stream>>>(pool, batch, Wout, bout, out, N);
}

// Round 9
// 415.150 us; speedup vs baseline: 2.1929x; 2.1929x over previous
//
#include <hip/hip_runtime.h>

#define EPS 1e-16f

typedef __attribute__((ext_vector_type(8))) short short8;
typedef __attribute__((ext_vector_type(4))) float f32x4;

// ---------- bf16 <-> fp32 (internal storage only) ----------
__device__ __forceinline__ float b2f(unsigned short u) {
    return __uint_as_float(((unsigned)u) << 16);
}
__device__ __forceinline__ unsigned short f2b(float f) {
    unsigned u = __float_as_uint(f);
    u += 0x7fffu + ((u >> 16) & 1u);  // round-to-nearest-even
    return (unsigned short)(u >> 16);
}

// ---------- async global->LDS (16B per lane; dst = base + lane*16) ----------
typedef __attribute__((address_space(3))) void lds_vp;
typedef __attribute__((address_space(1))) const void glb_vp;
__device__ __forceinline__ void load_lds16(const unsigned short* g,
                                           unsigned short* l) {
    __builtin_amdgcn_global_load_lds((glb_vp*)g, (lds_vp*)l, 16, 0, 0);
}

// ================= merged setup: wprep + init_deg + pool_init + wa1 =========
__global__ void setup_kernel(const float* __restrict__ W1,
                             const float* __restrict__ W2,
                             const float* __restrict__ W3,
                             unsigned short* __restrict__ wt2,
                             unsigned short* __restrict__ wt3,
                             unsigned short* __restrict__ w1sk,
                             const float* __restrict__ a1s,
                             const float* __restrict__ a1d,
                             float* __restrict__ w_as,
                             float* __restrict__ w_ad, int* __restrict__ deg,
                             float* __restrict__ pool, int N, int GC, int WB,
                             int DB, int PB) {
    int b = blockIdx.x, t = threadIdx.x;
    if (b < WB) {
        int i = b * 256 + t;
        if (i < 1024 * 512) {
            int k = i / 512, n = i % 512;
            wt2[(size_t)n * 1024 + k] = f2b(W2[i]);
        } else if (i < 1024 * 512 + 512 * 128) {
            int j = i - 1024 * 512;
            int k = j / 128, n = j % 128;
            wt3[(size_t)n * 512 + k] = f2b(W3[j]);
        } else if (i < 1024 * 512 + 512 * 128 + 8 * 128 * 32) {
            int q = i - (1024 * 512 + 512 * 128);
            int h = q >> 12, rem = q & 4095;
            int c = rem >> 5, kk = rem & 31;
            int off = (h == 7) ? 16 : 0;  // 16h - min(16h,96)
            float v = 0.f;
            int k = kk - off;
            if (k >= 0 && k < 11) v = W1[k * 1024 + h * 128 + c];
            w1sk[q] = f2b(v);
        }
    } else if (b < WB + DB) {
        int i = (b - WB) * 256 + t;
        if (i < N) deg[i] = 1;  // self-loop
    } else if (b < WB + DB + PB) {
        int i = (b - WB - DB) * 256 + t;
        if (i < GC) pool[i] = 0.f;
    } else {
        // wa1: w_as/w_ad = W1^T a1s / a1d, 88 active threads
        if (t < 88) {
            int h = t / 11, k = t % 11;
            float s = 0.f, d = 0.f;
            for (int c = 0; c < 128; c++) {
                float w = W1[k * 1024 + h * 128 + c];
                s += w * a1s[h * 128 + c];
                d += w * a1d[h * 128 + c];
            }
            w_as[h * 16 + k] = s;
            w_ad[h * 16 + k] = d;
        }
    }
}

// ============ merged: hist (deg atomics) + al1 (layer-1 logits) ============
__global__ void hist_al1_kernel(const int* __restrict__ ei, int E, int N,
                                int* __restrict__ deg,
                                const float* __restrict__ x,
                                const float* __restrict__ w_as,
                                const float* __restrict__ w_ad,
                                float* __restrict__ als,
                                float* __restrict__ ald, int EB) {
    int b = blockIdx.x, t = threadIdx.x;
    if (b < EB) {
        int e = b * 256 + t;
        if (e < E) {
            int d = ei[E + e];
            if ((unsigned)d < (unsigned)N) atomicAdd(&deg[d], 1);
        }
    } else {
        int i = (b - EB) * 256 + t;
        if (i < N * 8) {
            int n = i >> 3, h = i & 7;
            float s = 0.f, d = 0.f;
#pragma unroll
            for (int k = 0; k < 11; k++) {
                float xv = x[n * 11 + k];
                s += xv * w_as[h * 16 + k];
                d += xv * w_ad[h * 16 + k];
            }
            als[i] = s;
            ald[i] = d;
        }
    }
}

// ---------------------------- CSR build ----------------------------
__global__ void scan_block_kernel(const int* __restrict__ deg,
                                  int* __restrict__ rowst,
                                  int* __restrict__ bsum, int N) {
    __shared__ int s[256];
    int t = threadIdx.x, b = blockIdx.x;
    int i = b * 256 + t;
    s[t] = (i < N) ? deg[i] : 0;
    __syncthreads();
    for (int o = 1; o < 256; o <<= 1) {
        int a = (t >= o) ? s[t - o] : 0;
        __syncthreads();
        s[t] += a;
        __syncthreads();
    }
    if (i < N) rowst[i + 1] = s[t];
    if (t == 255) bsum[b] = s[255];
}

__global__ void scan_top_kernel(const int* __restrict__ bsum,
                                int* __restrict__ boff, int NB) {
    __shared__ int psum[65];
    int t = threadIdx.x;  // 64
    int chunk = (NB + 63) / 64;
    int lo = t * chunk, hi = lo + chunk;
    if (lo > NB) lo = NB;
    if (hi > NB) hi = NB;
    int s = 0;
    for (int i = lo; i < hi; i++) s += bsum[i];
    psum[t + 1] = s;
    __syncthreads();
    if (t == 0) {
        psum[0] = 0;
        for (int i = 1; i <= 64; i++) psum[i] += psum[i - 1];
    }
    __syncthreads();
    int run = psum[t];
    for (int i = lo; i < hi; i++) {
        boff[i] = run;  // exclusive
        run += bsum[i];
    }
}

// fused: add block offsets + place self-loop + init cursor
__global__ void scan_finish_kernel(int* __restrict__ rowst,
                                   const int* __restrict__ boff,
                                   const int* __restrict__ deg,
                                   int* __restrict__ srcs,
                                   int* __restrict__ cursor, int N) {
    int i = blockIdx.x * 256 + threadIdx.x;
    if (i == 0) rowst[0] = 0;
    if (i < N) {
        int incl = rowst[i + 1] + boff[blockIdx.x];
        rowst[i + 1] = incl;
        int st = incl - deg[i];
        srcs[st] = i;  // self-loop at row head
        cursor[i] = st + 1;
    }
}

// resolve source node at CSR build time
__global__ void scatter_kernel(const int* __restrict__ ei, int E, int N,
                               int* cursor, int* srcs) {
    int e = blockIdx.x * blockDim.x + threadIdx.x;
    if (e < E) {
        int d = ei[E + e];
        if ((unsigned)d < (unsigned)N) {
            int p = atomicAdd(&cursor[d], 1);
            int s = ei[e];
            if ((unsigned)s >= (unsigned)N) s = d;
            srcs[p] = s;
        }
    }
}

// ------ fused layer-1 softmax + x-aggregation ------
__global__ void agg1_fused(const float* __restrict__ x,
                           const float* __restrict__ als,
                           const float* __restrict__ ald,
                           const int* __restrict__ rowst,
                           const int* __restrict__ srcs,
                           unsigned short* __restrict__ A2, int N) {
    constexpr int MAXE = 64;
    __shared__ float sv[MAXE * 8];
    __shared__ float sx[MAXE * 12];  // 11 cols, pad to 12
    int n = blockIdx.x;
    int t = threadIdx.x;  // 128
    int h = t >> 4, k = t & 15;
    int start = rowst[n], end = rowst[n + 1];
    int deg = end - start;
    float acc = 0.f;

    if (deg <= MAXE) {
        // phase A: each (edge,head) logit exactly once + x-row stage
        for (int p = t; p < deg * 8; p += 128) {
            int e = p >> 3, hh = p & 7;
            int s = srcs[start + e];
            float v = als[s * 8 + hh] + ald[n * 8 + hh];
            sv[e * 8 + hh] = v > 0.f ? v : 0.2f * v;
        }
        for (int p = t; p < deg * 16; p += 128) {
            int e = p >> 4, kx = p & 15;
            if (kx < 11)
                sx[e * 12 + kx] = x[(size_t)srcs[start + e] * 11 + kx];
        }
        __syncthreads();
        // phase B: per-head softmax (16-lane reduce)
        float m = -1e30f;
        for (int e = k; e < deg; e += 16) m = fmaxf(m, sv[e * 8 + h]);
#pragma unroll
        for (int o = 1; o < 16; o <<= 1) m = fmaxf(m, __shfl_xor(m, o));
        float ee[(MAXE + 15) / 16];
        float den = 0.f;
        {
            int kk = 0;
            for (int e = k; e < deg; e += 16, kk++) {
                float xv = expf(sv[e * 8 + h] - m);
                ee[kk] = xv;
                den += xv;
            }
        }
#pragma unroll
        for (int o = 1; o < 16; o <<= 1) den += __shfl_xor(den, o);
        float dinv = 1.0f / (den + EPS);
        {
            int kk = 0;
            for (int e = k; e < deg; e += 16, kk++)
                sv[e * 8 + h] = ee[kk] * dinv;
        }
        __syncthreads();
        // phase C: pure LDS FMA
        const int CH = 4;
        for (int e = 0; e < deg; e += CH) {
            int mc = deg - e;
            if (mc > CH) mc = CH;
            float al[CH], xv[CH];
#pragma unroll
            for (int j = 0; j < CH; j++)
                if (j < mc) {
                    al[j] = sv[(e + j) * 8 + h];
                    xv[j] = (k < 11) ? sx[(e + j) * 12 + k] : 0.f;
                }
#pragma unroll
            for (int j = 0; j < CH; j++)
                if (j < mc) acc += al[j] * xv[j];
        }
    } else {
        // slow path (deg > 64, rare): recompute alpha on the fly
        float aldn = ald[n * 8 + h];
        float m = -1e30f;
        for (int idx = start + k; idx < end; idx += 16) {
            float v = als[srcs[idx] * 8 + h] + aldn;
            v = v > 0.f ? v : 0.2f * v;
            m = fmaxf(m, v);
        }
#pragma unroll
        for (int o = 1; o < 16; o <<= 1) m = fmaxf(m, __shfl_xor(m, o));
        float den = 0.f;
        for (int idx = start + k; idx < end; idx += 16) {
            float v = als[srcs[idx] * 8 + h] + aldn;
            v = v > 0.f ? v : 0.2f * v;
            den += expf(v - m);
        }
#pragma unroll
        for (int o = 1; o < 16; o <<= 1) den += __shfl_xor(den, o);
        float dinv = 1.0f / (den + EPS);
        for (int idx = start; idx < end; idx++) {
            int s = srcs[idx];
            float v = als[s * 8 + h] + aldn;
            v = v > 0.f ? v : 0.2f * v;
            float a = expf(v - m) * dinv;
            float xv = (k < 11) ? x[s * 11 + k] : 0.f;
            acc += a * xv;
        }
    }
    A2[(size_t)n * 128 + t] = f2b(acc);
}

// MFMA GEMM (legacy 2-phase, BK=32): used only for layer-1 small-K path.
template <bool EPI, int HB, int CC, bool SK>
__global__ __launch_bounds__(256) void gemm_mfma(
    const unsigned short* __restrict__ A, const unsigned short* __restrict__ Bt,
    unsigned short* __restrict__ C, const float* __restrict__ bias,
    const float* __restrict__ a_s, const float* __restrict__ a_d,
    float* __restrict__ als, float* __restrict__ ald, int H, int M, int N,
    int K, int lda) {
    int NX = gridDim.x;
    int bid = blockIdx.y * NX + blockIdx.x;
    int win = bid & (8 * NX - 1);
    int mg = bid / (8 * NX);
    int m_t = mg * 8 + (win & 7);
    int n_t = win >> 3;
    int bm = m_t * 128, bn = n_t * 128;
    if (bm >= M) return;

    union SMem {
        struct {
            unsigned short As[2][128 * 32];
            unsigned short Bs[2][128 * 32];
        } k;                            // 32 KB, live during K-loop
        unsigned short Ct[128 * 132];   // 33.8 KB, live during epilogue
    };
    __shared__ __align__(16) SMem sm;
    auto& As = sm.k.As;
    auto& Bs = sm.k.Bs;
    auto& Ct = sm.Ct;

    int t = threadIdx.x;
    int w = t >> 6, lane = t & 63;
    int quad = lane >> 4, l16 = lane & 15;
    int wr = (w >> 1) * 64, wc = (w & 1) * 64;

    int kofs = 0;
    const unsigned short* Bb = Bt;
    if (SK) {
        kofs = n_t * 16;
        if (kofs > lda - 32) kofs = lda - 32;
        Bb = Bt + (size_t)n_t * 128 * 32;
    }

    int c0 = w * 128 + lane;
    int c1 = c0 + 64;
    int r0 = c0 >> 2, p0 = c0 & 3;
    int r1 = c1 >> 2, p1 = c1 & 3;
    int j0 = (p0 - (r0 >> 1)) & 3;
    int j1 = (p1 - (r1 >> 1)) & 3;
    int ga0 = bm + r0;
    if (ga0 >= M) ga0 = M - 1;
    int ga1 = bm + r1;
    if (ga1 >= M) ga1 = M - 1;
    const unsigned short* Ag0 = A + (size_t)ga0 * lda + kofs + j0 * 8;
    const unsigned short* Ag1 = A + (size_t)ga1 * lda + kofs + j1 * 8;
    size_t br0 = SK ? (size_t)r0 : (size_t)(bn + r0);
    size_t br1 = SK ? (size_t)r1 : (size_t)(bn + r1);
    const unsigned short* Bg0 = Bb + br0 * K + j0 * 8;
    const unsigned short* Bg1 = Bb + br1 * K + j1 * 8;

    auto stage = [&](int st, int k0) {
        load_lds16(Ag0 + k0, &As[st][(w * 128) * 8]);
        load_lds16(Ag1 + k0, &As[st][(w * 128 + 64) * 8]);
        load_lds16(Bg0 + k0, &Bs[st][(w * 128) * 8]);
        load_lds16(Bg1 + k0, &Bs[st][(w * 128 + 64) * 8]);
    };

    int aoff[4], boff4[4];
#pragma unroll
    for (int i = 0; i < 4; i++) {
        int ra = wr + i * 16 + l16;
        aoff[i] = ra * 32 + (((quad + (ra >> 1)) & 3) * 8);
        int rb = wc + i * 16 + l16;
        boff4[i] = rb * 32 + (((quad + (rb >> 1)) & 3) * 8);
    }

    f32x4 acc[4][4] = {};
    stage(0, 0);
    int st = 0;
    for (int k0 = 0; k0 < K; k0 += 32, st ^= 1) {
        __syncthreads();
        if (k0 + 32 < K) stage(st ^ 1, k0 + 32);
        short8 a[4], b[4];
#pragma unroll
        for (int mi = 0; mi < 4; mi++) a[mi] = *(const short8*)&As[st][aoff[mi]];
#pragma unroll
        for (int ni = 0; ni < 4; ni++) b[ni] = *(const short8*)&Bs[st][boff4[ni]];
#pragma unroll
        for (int mi = 0; mi < 4; mi++)
#pragma unroll
            for (int ni = 0; ni < 4; ni++)
                acc[mi][ni] = __builtin_amdgcn_mfma_f32_16x16x32_bf16(
                    a[mi], b[ni], acc[mi][ni], 0, 0, 0);
    }
    __syncthreads();  // all waves done with As/Bs before Ct overlays them

#pragma unroll
    for (int mi = 0; mi < 4; mi++) {
#pragma unroll
        for (int r = 0; r < 4; r++) {
            int rl = wr + mi * 16 + quad * 4 + r;
#pragma unroll
            for (int ni = 0; ni < 4; ni++) {
                int cl = wc + ni * 16 + l16;
                float v = acc[mi][ni][r];
                if (EPI) {
                    v += bias[bn + cl];
                    v = v > 0.f ? v : 0.01f * v;
                }
                Ct[rl * 132 + cl] = f2b(v);
            }
        }
    }
    __syncthreads();
#pragma unroll
    for (int p = 0; p < 16; p++) {
        int q = p * 256 + t;
        int row = q >> 5, c8 = q & 31;
        if (bm + row < M) {
            uint2 v = *(const uint2*)&Ct[row * 132 + c8 * 4];
            *(uint2*)&C[(size_t)(bm + row) * N + bn + c8 * 4] = v;
        }
    }
    if (HB > 0) {
        for (int pi = t; pi < 128 * HB; pi += 256) {
            int row = pi / HB, hl = pi % HB;
            if (bm + row >= M) continue;
            int hg = bn / CC + hl;
            const unsigned short* rp = &Ct[row * 132 + hl * CC];
            const float* asp = a_s + hg * CC;
            const float* adp = a_d + hg * CC;
            float s = 0.f, d = 0.f;
#pragma unroll
            for (int c = 0; c < CC; c++) {
                float v = b2f(rp[c]);
                s += v * asp[c];
                d += v * adp[c];
            }
            als[(size_t)(bm + row) * H + hg] = s;
            ald[(size_t)(bm + row) * H + hg] = d;
        }
    }
}

// ================== pipelined MFMA GEMM (layers 2 & 3) ==================
// BM=BN=128, BK=64, 4 waves (64x64 each), double-buffered 64 KB LDS.
// Counted-vmcnt schedule; raw s_barrier; XOR slot swizzle with
// inverse-swizzled global source. K % 64 == 0, lda == K, N % 128 == 0.
// At 2 blocks/CU this runs at the per-CU LDS-BW roofline (~124 B/cyc).
template <int HB, int CC>
__global__ __launch_bounds__(256, 2) void gemm_pipe(
    const unsigned short* __restrict__ A, const unsigned short* __restrict__ Bt,
    unsigned short* __restrict__ C, const float* __restrict__ a_s,
    const float* __restrict__ a_d, float* __restrict__ als,
    float* __restrict__ ald, int H, int M, int N, int K) {
    int NX = gridDim.x;
    int bid = blockIdx.y * NX + blockIdx.x;
    int win = bid & (8 * NX - 1);
    int mg = bid / (8 * NX);
    int m_t = mg * 8 + (win & 7);
    int n_t = win >> 3;
    int bm = m_t * 128, bn = n_t * 128;
    if (bm >= M) return;

    union SMem {
        struct {
            unsigned short As[2][128 * 64];
            unsigned short Bs[2][128 * 64];
        } k;                            // 64 KB, live during K-loop
        unsigned short Ct[128 * 132];   // 33.8 KB, live during epilogue
    };
    __shared__ __align__(16) SMem sm;

    int t = threadIdx.x;
    int w = t >> 6, lane = t & 63;
    int quad = lane >> 4, l16 = lane & 15;
    int wr = (w >> 1) * 64, wc = (w & 1) * 64;

    int srow = lane >> 3;            // row&7 for this lane's chunks
    int gsl = (lane & 7) ^ srow;     // inverse-swizzled global slot
    const unsigned short* Ag[4];
    const unsigned short* Bg[4];
#pragma unroll
    for (int j = 0; j < 4; j++) {
        int row = (j * 4 + w) * 8 + srow;  // 0..127
        int ga = bm + row;
        if (ga > M - 1) ga = M - 1;
        Ag[j] = A + (size_t)ga * K + gsl * 8;
        Bg[j] = Bt + (size_t)(bn + row) * K + gsl * 8;
    }
    auto stage = [&](int st, int kt) {
        int ko = kt * 64;
#pragma unroll
        for (int j = 0; j < 4; j++) {
            load_lds16(Ag[j] + ko, &sm.k.As[st][(j * 4 + w) * 512]);
            load_lds16(Bg[j] + ko, &sm.k.Bs[st][(j * 4 + w) * 512]);
        }
    };

    int arow[4], brow[4];
#pragma unroll
    for (int i = 0; i < 4; i++) {
        arow[i] = (wr + i * 16 + l16) * 64;
        brow[i] = (wc + i * 16 + l16) * 64;
    }
    int sw = l16 & 7;

    f32x4 acc[4][4] = {};
    int NT = K >> 6;
    stage(0, 0);
    if (NT > 1) stage(1, 1);
    for (int tt = 0; tt < NT; tt++) {
        int bb = tt & 1;
        if (tt + 1 < NT)
            asm volatile("s_waitcnt vmcnt(8)" ::: "memory");
        else
            asm volatile("s_waitcnt vmcnt(0)" ::: "memory");
        __builtin_amdgcn_s_barrier();
        __builtin_amdgcn_sched_barrier(0);  // no frag read above the barrier
#pragma unroll
        for (int ks = 0; ks < 2; ks++) {
            short8 a[4], b[4];
            int so = ((ks * 4 + quad) ^ sw) * 8;
#pragma unroll
            for (int mi = 0; mi < 4; mi++)
                a[mi] = *(const short8*)&sm.k.As[bb][arow[mi] + so];
#pragma unroll
            for (int ni = 0; ni < 4; ni++)
                b[ni] = *(const short8*)&sm.k.Bs[bb][brow[ni] + so];
            __builtin_amdgcn_s_setprio(1);
#pragma unroll
            for (int mi = 0; mi < 4; mi++)
#pragma unroll
                for (int ni = 0; ni < 4; ni++)
                    acc[mi][ni] = __builtin_amdgcn_mfma_f32_16x16x32_bf16(
                        a[mi], b[ni], acc[mi][ni], 0, 0, 0);
            __builtin_amdgcn_s_setprio(0);
        }
        asm volatile("s_waitcnt lgkmcnt(0)" ::: "memory");
        __builtin_amdgcn_s_barrier();  // all waves done reading buf bb
        if (tt + 2 < NT) stage(bb, tt + 2);
    }
    __syncthreads();  // K-loop fully drained before Ct overlays As/Bs

#pragma unroll
    for (int mi = 0; mi < 4; mi++) {
#pragma unroll
        for (int r = 0; r < 4; r++) {
            int rl = wr + mi * 16 + quad * 4 + r;
#pragma unroll
            for (int ni = 0; ni < 4; ni++) {
                int cl = wc + ni * 16 + l16;
                sm.Ct[rl * 132 + cl] = f2b(acc[mi][ni][r]);
            }
        }
    }
    __syncthreads();
#pragma unroll
    for (int p = 0; p < 16; p++) {
        int q = p * 256 + t;
        int row = q >> 5, c8 = q & 31;
        if (bm + row < M) {
            uint2 v = *(const uint2*)&sm.Ct[row * 132 + c8 * 4];
            *(uint2*)&C[(size_t)(bm + row) * N + bn + c8 * 4] = v;
        }
    }
    if (HB > 0) {
        for (int pi = t; pi < 128 * HB; pi += 256) {
            int row = pi / HB, hl = pi % HB;
            if (bm + row >= M) continue;
            int hg = bn / CC + hl;
            const unsigned short* rp = &sm.Ct[row * 132 + hl * CC];
            const float* asp = a_s + hg * CC;
            const float* adp = a_d + hg * CC;
            float s = 0.f, d = 0.f;
#pragma unroll
            for (int c = 0; c < CC; c++) {
                float v = b2f(rp[c]);
                s += v * asp[c];
                d += v * adp[c];
            }
            als[(size_t)(bm + row) * H + hg] = s;
            ald[(size_t)(bm + row) * H + hg] = d;
        }
    }
}

// ------ fused softmax + aggregation, 1 wave, 8 cols/thread (layer 2) ------
// 64 threads; thread t owns cols c=t*8..t*8+7 of head hh=t>>3; TPH=8.
// ushort8 gathers: 16 B/lane -> one full 1 KB row per wave instruction.
template <int H, int C>
__global__ void agg_fused4(const unsigned short* __restrict__ hin,
                           const float* __restrict__ als,
                           const float* __restrict__ ald,
                           const int* __restrict__ rowst,
                           const int* __restrict__ srcs,
                           const float* __restrict__ bias,
                           unsigned short* __restrict__ out, int N) {
    constexpr int HC = H * C;        // 512
    constexpr int NT = HC / 8;       // 64 threads
    constexpr int TPH = C / 8;       // 8 lanes per head
    constexpr int MAXE = 64;
    __shared__ float sv[MAXE * H];   // logits -> alphas
    __shared__ int ssrc[MAXE];
    int n = blockIdx.x;
    int t = threadIdx.x;
    int c = t * 8;
    int hh = c / C;
    int li = (c % C) / 8;
    int start = rowst[n], end = rowst[n + 1];
    int deg = end - start;
    float acc[8] = {};

    if (deg <= MAXE) {
        // phase A: each (edge,head) logit exactly once
        for (int p = t; p < deg * H; p += NT) {
            int e = p / H, h = p % H;
            int s = srcs[start + e];
            if (h == 0) ssrc[e] = s;
            float v = als[s * H + h] + ald[n * H + h];
            sv[e * H + h] = v > 0.f ? v : 0.2f * v;
        }
        __syncthreads();
        // phase B: per-head softmax (8-lane reduce)
        float m = -1e30f;
        for (int e = li; e < deg; e += TPH) m = fmaxf(m, sv[e * H + hh]);
#pragma unroll
        for (int o = 1; o < TPH; o <<= 1) m = fmaxf(m, __shfl_xor(m, o));
        float ee[(MAXE + TPH - 1) / TPH];
        float den = 0.f;
        {
            int k = 0;
            for (int e = li; e < deg; e += TPH, k++) {
                float x = expf(sv[e * H + hh] - m);
                ee[k] = x;
                den += x;
            }
        }
#pragma unroll
        for (int o = 1; o < TPH; o <<= 1) den += __shfl_xor(den, o);
        float dinv = 1.0f / (den + EPS);
        {
            int k = 0;
            for (int e = li; e < deg; e += TPH, k++)
                sv[e * H + hh] = ee[k] * dinv;
        }
        __syncthreads();
        // phase C: pure gather + FMA (16 B loads)
        const int CH = 4;
        for (int e = 0; e < deg; e += CH) {
            int mc = deg - e;
            if (mc > CH) mc = CH;
            int ss[CH];
            float al[CH];
            short8 uv[CH];
#pragma unroll
            for (int j = 0; j < CH; j++)
                if (j < mc) {
                    ss[j] = ssrc[e + j];
                    al[j] = sv[(e + j) * H + hh];
                }
#pragma unroll
            for (int j = 0; j < CH; j++)
                if (j < mc)
                    uv[j] = *(const short8*)(hin + (size_t)ss[j] * HC + c);
#pragma unroll
            for (int j = 0; j < CH; j++)
                if (j < mc) {
                    float a = al[j];
#pragma unroll
                    for (int q = 0; q < 8; q++)
                        acc[q] += a * b2f((unsigned short)uv[j][q]);
                }
        }
    } else {
        // slow path (deg > MAXE, rare): per-thread recompute
        float aldn = ald[n * H + hh];
        float m = -1e30f;
        for (int idx = start + li; idx < end; idx += TPH) {
            float v = als[srcs[idx] * H + hh] + aldn;
            v = v > 0.f ? v : 0.2f * v;
            m = fmaxf(m, v);
        }
#pragma unroll
        for (int o = 1; o < TPH; o <<= 1) m = fmaxf(m, __shfl_xor(m, o));
        float den = 0.f;
        for (int idx = start + li; idx < end; idx += TPH) {
            float v = als[srcs[idx] * H + hh] + aldn;
            v = v > 0.f ? v : 0.2f * v;
            den += expf(v - m);
        }
#pragma unroll
        for (int o = 1; o < TPH; o <<= 1) den += __shfl_xor(den, o);
        float dinv = 1.0f / (den + EPS);
        for (int idx = start; idx < end; idx++) {
            int s = srcs[idx];
            float v = als[s * H + hh] + aldn;
            v = v > 0.f ? v : 0.2f * v;
            float a = expf(v - m) * dinv;
            short8 uv = *(const short8*)(hin + (size_t)s * HC + c);
#pragma unroll
            for (int q = 0; q < 8; q++)
                acc[q] += a * b2f((unsigned short)uv[q]);
        }
    }
    short8 o8;
#pragma unroll
    for (int q = 0; q < 8; q++) {
        float v = acc[q] + bias[c + q];
        v = v > 0.f ? v : 0.01f * v;
        o8[q] = (short)f2b(v);
    }
    *(short8*)&out[(size_t)n * HC + c] = o8;
}

// ------ fused softmax + aggregation, ushort2 (layer 3) ------
template <int H, int C>
__global__ void agg_fused2(const unsigned short* __restrict__ hin,
                           const float* __restrict__ als,
                           const float* __restrict__ ald,
                           const int* __restrict__ rowst,
                           const int* __restrict__ srcs,
                           const float* __restrict__ bias,
                           unsigned short* __restrict__ out, int N) {
    constexpr int HC = H * C;        // 128
    constexpr int NT = HC / 2;       // 64 threads
    constexpr int TPH = C / 2;       // 16 lanes per head
    constexpr int MAXE = 64;
    __shared__ float sv[MAXE * H];
    __shared__ int ssrc[MAXE];
    int n = blockIdx.x;
    int t = threadIdx.x;
    int c = t * 2;
    int hh = c / C;
    int li = (c % C) / 2;
    int start = rowst[n], end = rowst[n + 1];
    int deg = end - start;
    float a0 = 0.f, a1 = 0.f;

    if (deg <= MAXE) {
        for (int p = t; p < deg * H; p += NT) {
            int e = p / H, h = p % H;
            int s = srcs[start + e];
            if (h == 0) ssrc[e] = s;
            float v = als[s * H + h] + ald[n * H + h];
            sv[e * H + h] = v > 0.f ? v : 0.2f * v;
        }
        __syncthreads();
        float m = -1e30f;
        for (int e = li; e < deg; e += TPH) m = fmaxf(m, sv[e * H + hh]);
#pragma unroll
        for (int o = 1; o < TPH; o <<= 1) m = fmaxf(m, __shfl_xor(m, o));
        float ee[(MAXE + TPH - 1) / TPH];
        float den = 0.f;
        {
            int k = 0;
            for (int e = li; e < deg; e += TPH, k++) {
                float x = expf(sv[e * H + hh] - m);
                ee[k] = x;
                den += x;
            }
        }
#pragma unroll
        for (int o = 1; o < TPH; o <<= 1) den += __shfl_xor(den, o);
        float dinv = 1.0f / (den + EPS);
        {
            int k = 0;
            for (int e = li; e < deg; e += TPH, k++)
                sv[e * H + hh] = ee[k] * dinv;
        }
        __syncthreads();
        const int CH = 4;
        for (int e = 0; e < deg; e += CH) {
            int mc = deg - e;
            if (mc > CH) mc = CH;
            int ss[CH];
            float al[CH];
            ushort2 uv[CH];
#pragma unroll
            for (int j = 0; j < CH; j++)
                if (j < mc) {
                    ss[j] = ssrc[e + j];
                    al[j] = sv[(e + j) * H + hh];
                }
#pragma unroll
            for (int j = 0; j < CH; j++)
                if (j < mc)
                    uv[j] = *(const ushort2*)(hin + (size_t)ss[j] * HC + c);
#pragma unroll
            for (int j = 0; j < CH; j++)
                if (j < mc) {
                    a0 += al[j] * b2f(uv[j].x);
                    a1 += al[j] * b2f(uv[j].y);
                }
        }
    } else {
        float aldn = ald[n * H + hh];
        float m = -1e30f;
        for (int idx = start + li; idx < end; idx += TPH) {
            float v = als[srcs[idx] * H + hh] + aldn;
            v = v > 0.f ? v : 0.2f * v;
            m = fmaxf(m, v);
        }
#pragma unroll
        for (int o = 1; o < TPH; o <<= 1) m = fmaxf(m, __shfl_xor(m, o));
        float den = 0.f;
        for (int idx = start + li; idx < end; idx += TPH) {
            float v = als[srcs[idx] * H + hh] + aldn;
            v = v > 0.f ? v : 0.2f * v;
            den += expf(v - m);
        }
#pragma unroll
        for (int o = 1; o < TPH; o <<= 1) den += __shfl_xor(den, o);
        float dinv = 1.0f / (den + EPS);
        const int CH = 4;
        for (int idx = start; idx < end; idx += CH) {
            int mc = end - idx;
            if (mc > CH) mc = CH;
            int ss[CH];
            float lv[CH];
            ushort2 uv[CH];
#pragma unroll
            for (int j = 0; j < CH; j++)
                if (j < mc) ss[j] = srcs[idx + j];
#pragma unroll
            for (int j = 0; j < CH; j++)
                if (j < mc) lv[j] = als[ss[j] * H + hh];
#pragma unroll
            for (int j = 0; j < CH; j++)
                if (j < mc)
                    uv[j] = *(const ushort2*)(hin + (size_t)ss[j] * HC + c);
#pragma unroll
            for (int j = 0; j < CH; j++)
                if (j < mc) {
                    float v = lv[j] + aldn;
                    v = v > 0.f ? v : 0.2f * v;
                    float a = expf(v - m) * dinv;
                    a0 += a * b2f(uv[j].x);
                    a1 += a * b2f(uv[j].y);
                }
        }
    }
    float v0 = a0 + bias[c], v1 = a1 + bias[c + 1];
    ushort2 o;
    o.x = f2b(v0 > 0.f ? v0 : 0.01f * v0);
    o.y = f2b(v1 > 0.f ? v1 : 0.01f * v1);
    *(ushort2*)&out[(size_t)n * HC + c] = o;
}

// ---------------------- parallel mean-pool + head ----------------------
__global__ void pool_partial_kernel(const unsigned short* __restrict__ h3,
                                    const int* __restrict__ batch,
                                    float* __restrict__ pool, int N, int G) {
    int lo = blockIdx.x * 128;
    int hi = lo + 128;
    if (hi > N) hi = N;
    if (lo >= N) return;
    int t = threadIdx.x;  // 128
    int cur = batch[lo];
    float acc = 0.f;
    for (int n = lo; n < hi; n++) {
        int g = batch[n];
        if (g != cur) {
            if ((unsigned)cur < (unsigned)G) atomicAdd(&pool[cur * 128 + t], acc);
            acc = 0.f;
            cur = g;
        }
        acc += b2f(h3[(size_t)n * 128 + t]);
    }
    if ((unsigned)cur < (unsigned)G) atomicAdd(&pool[cur * 128 + t], acc);
}

__global__ void head_kernel(const float* __restrict__ pool,
                            const int* __restrict__ batch,
                            const float* __restrict__ Wout,
                            const float* __restrict__ bout,
                            float* __restrict__ out, int N) {
    int g = blockIdx.x;
    int t = threadIdx.x;  // 128
    int lo, hi;
    {
        int a = 0, b = N;
        while (a < b) { int mid = (a + b) >> 1; if (batch[mid] < g) a = mid + 1; else b = mid; }
        lo = a;
        a = lo; b = N;
        while (a < b) { int mid = (a + b) >> 1; if (batch[mid] < g + 1) a = mid + 1; else b = mid; }
        hi = a;
    }
    float c = (float)(hi - lo);
    c = c > 1.f ? c : 1.f;
    float v = (pool[g * 128 + t] / c) * Wout[t];
    for (int o = 32; o; o >>= 1) v += __shfl_xor(v, o);
    __shared__ float partial[2];
    if ((t & 63) == 0) partial[t >> 6] = v;
    __syncthreads();
    if (t == 0) out[g] = partial[0] + partial[1] + bout[0];
}

// ---------------------------- host orchestration ----------------------------
extern "C" void kernel_launch(void* const* d_in, const int* in_sizes, int n_in,
                              void* d_out, int out_size, void* d_ws,
                              size_t ws_size, hipStream_t stream) {
    const float* x = (const float*)d_in[0];
    const int* ei = (const int*)d_in[1];
    const int* batch = (const int*)d_in[2];
    const float* W1 = (const float*)d_in[3];
    const float* a1s = (const float*)d_in[4];
    const float* a1d = (const float*)d_in[5];
    const float* b1 = (const float*)d_in[6];
    const float* W2 = (const float*)d_in[7];
    const float* a2s = (const float*)d_in[8];
    const float* a2d = (const float*)d_in[9];
    const float* b2 = (const float*)d_in[10];
    const float* W3 = (const float*)d_in[11];
    const float* a3s = (const float*)d_in[12];
    const float* a3d = (const float*)d_in[13];
    const float* b3 = (const float*)d_in[14];
    const float* Wout = (const float*)d_in[15];
    const float* bout = (const float*)d_in[16];
    float* out = (float*)d_out;

    const int N = in_sizes[0] / 11;
    const int E = in_sizes[1] / 2;
    const int Etot = E + N;
    const int G = out_size;
    const int NB = (N + 255) / 256;
    const int MT = ((N + 127) / 128 + 7) / 8 * 8;  // M-tiles padded to x8

    char* ws = (char*)d_ws;
    size_t off = 0;
    auto alloc = [&](size_t bytes) -> void* {
        void* p = ws + off;
        off += (bytes + 255) & ~(size_t)255;
        return p;
    };
    unsigned short* buf1 = (unsigned short*)alloc((size_t)N * 1024 * 2);  // h
    unsigned short* buf2 = (unsigned short*)alloc((size_t)N * 1024 * 2);  // out
    float* als = (float*)alloc((size_t)N * 8 * 4);
    float* ald = (float*)alloc((size_t)N * 8 * 4);
    int* rowst = (int*)alloc((size_t)(N + 1) * 4);
    int* cursor = (int*)alloc((size_t)N * 4);
    int* srcs = (int*)alloc((size_t)Etot * 4);
    int* deg = (int*)alloc((size_t)N * 4);
    int* bsum = (int*)alloc((size_t)NB * 4);
    int* boff = (int*)alloc((size_t)NB * 4);
    float* pool = (float*)alloc((size_t)G * 128 * 4);
    unsigned short* aggx = (unsigned short*)alloc((size_t)N * 128 * 2);
    unsigned short* w1sk = (unsigned short*)alloc((size_t)8 * 128 * 32 * 2);
    unsigned short* wt2 = (unsigned short*)alloc((size_t)1024 * 512 * 2);
    unsigned short* wt3 = (unsigned short*)alloc((size_t)512 * 128 * 2);
    float* w_as = (float*)alloc(8 * 16 * 4);
    float* w_ad = (float*)alloc(8 * 16 * 4);

    int nb = (N + 255) / 256;
    int eb = (E + 255) / 256;

    // ---- merged setup: wprep + init_deg + pool_init + wa1 (1 launch) ----
    const int WTOT = 1024 * 512 + 512 * 128 + 8 * 128 * 32;
    const int WB = (WTOT + 255) / 256;
    const int PB = (G * 128 + 255) / 256;
    setup_kernel<<<WB + nb + PB + 1, 256, 0, stream>>>(
        W1, W2, W3, wt2, wt3, w1sk, a1s, a1d, w_as, w_ad, deg, pool, N,
        G * 128, WB, nb, PB);

    // ---- merged hist + al1 (both depend only on setup, 1 launch) ----
    const int AB = (N * 8 + 255) / 256;
    hist_al1_kernel<<<eb + AB, 256, 0, stream>>>(ei, E, N, deg, x, w_as, w_ad,
                                                 als, ald, eb);

    // ---- CSR scan + scatter ----
    scan_block_kernel<<<NB, 256, 0, stream>>>(deg, rowst, bsum, N);
    scan_top_kernel<<<1, 64, 0, stream>>>(bsum, boff, NB);
    scan_finish_kernel<<<NB, 256, 0, stream>>>(rowst, boff, deg, srcs, cursor,
                                               N);
    scatter_kernel<<<eb, 256, 0, stream>>>(ei, E, N, cursor, srcs);

    // ---- Layer 1 (linearity trick) ----
    agg1_fused<<<N, 128, 0, stream>>>(x, als, ald, rowst, srcs, aggx, N);
    gemm_mfma<true, 0, 1, true><<<dim3(8, MT), 256, 0, stream>>>(
        aggx, w1sk, buf2, b1, nullptr, nullptr, nullptr, nullptr, 0, N, 1024,
        32, 128);

    // ---- Layer 2: pipelined gemm (h2 + fused al) -> fused softmax+agg ----
    gemm_pipe<2, 64><<<dim3(4, MT), 256, 0, stream>>>(
        buf2, wt2, buf1, a2s, a2d, als, ald, 8, N, 512, 1024);
    agg_fused4<8, 64><<<N, 64, 0, stream>>>(buf1, als, ald, rowst, srcs, b2,
                                            buf2, N);

    // ---- Layer 3: pipelined gemm (h3 + fused al) -> fused softmax+agg ----
    gemm_pipe<4, 32><<<dim3(1, MT), 256, 0, stream>>>(
        buf2, wt3, buf1, a3s, a3d, als, ald, 4, N, 128, 512);
    agg_fused2<4, 32><<<N, 64, 0, stream>>>(buf1, als, ald, rowst, srcs, b3,
                                            buf2, N);

    // ---- parallel mean-pool + head ----
    pool_partial_kernel<<<(N + 127) / 128, 128, 0, stream>>>(buf2, batch, pool,
                                                             N, G);
    head_kernel<<<G, 128, 0, stream>>>(pool, batch, Wout, bout, out, N);
}